// Round 17
// baseline (195.862 us; speedup 1.0000x reference)
//
#include <hip/hip_runtime.h>
#include <hip/hip_bf16.h>
#include <math.h>

// SIREN eigenfunction banks + small linear head.
// eigen: persistent-e, 256-thr / 32-t blocks (4 waves: wo 0..3), proven
// algebra. NEW vs R16: 2 barriers/iter — L0(it+1) moved into the L2/final
// region AFTER final consumes acc (R14's spill came from acc-live-across-L0).

typedef short  bf16x8 __attribute__((ext_vector_type(8)));
typedef float  f32x4  __attribute__((ext_vector_type(4)));
typedef unsigned short u16;
typedef u16    u16x8  __attribute__((ext_vector_type(8)));
typedef unsigned int u32;
typedef u32    u32x4  __attribute__((ext_vector_type(4)));

constexpr int DD    = 128;
constexpr int E_TOT = 1024;
constexpr int T_INc = 512;
constexpr int T_OUTc= 256;
constexpr int BBc   = 32;
constexpr int CCc   = 64;
constexpr int NB1   = 17;
constexpr int EF_W  = NB1 * CCc;     // 1088
constexpr int LIN_I = EF_W + 4;      // 1092
constexpr int LIN_O = EF_W;          // 1088

// packed RNE pair via compiler intrinsic: low 16 bits = cvt(a), high = cvt(b)
__device__ __forceinline__ u32 pkrn(float a, float b) {
  __hip_bfloat162 h = __float22bfloat162_rn(float2{a, b});
  u32 r;
  __builtin_memcpy(&r, &h, 4);
  return r;
}

// XOR-swizzled element index into a row-major [rows][128] u16 LDS plane.
// byte = row*256 + ((col*2) ^ ((row&15)<<4)); 16B-chunk preserving. (proven)
__device__ __forceinline__ int swz(int row, int col) {
  return row * DD + ((((col << 1) ^ ((row & 15) << 4)) >> 1));
}

// ---------------------------------------------------------------------------
// eigen_persist: grid = 2*E_TOT. Blocks [0,1024): T_IN; [1024,2048): T_OUT.
// 4 waves = wo 0..3; per 32-t iter each wave computes 32t x 32o.
// Loop: {L1, act1, BAR_A, L2, final, L0(it+1), BAR_B, epilogue}.
// ---------------------------------------------------------------------------
__global__ __launch_bounds__(256, 4) void eigen_persist(
    const float* __restrict__ W0i, const float* __restrict__ b0i,
    const float* __restrict__ Whi, const float* __restrict__ bhi,
    const float* __restrict__ Wli, const float* __restrict__ bli,
    const float* __restrict__ w0ii, float* __restrict__ efni,
    const float* __restrict__ W0o, const float* __restrict__ b0o,
    const float* __restrict__ Who, const float* __restrict__ bho,
    const float* __restrict__ Wlo, const float* __restrict__ blo,
    const float* __restrict__ w0io, float* __restrict__ efno)
{
  __shared__ u16 xP[2][4096];          // x0 / x1 planes (32x128 bf16, swizzled)
  __shared__ float yPart[4 * 32];      // per-wo partial y[t]
  __shared__ float w0s[128], b0s[128];

  const bool isIn = (blockIdx.x < E_TOT);
  const int  e    = blockIdx.x & (E_TOT - 1);
  const int  NIT  = isIn ? (T_INc / 32) : (T_OUTc / 32);
  const float tstep = isIn ? (1.0f / (float)(T_INc - 1)) : (1.0f / (float)(T_OUTc - 1));
  const float* W0 = isIn ? W0i : W0o;
  const float* b0 = isIn ? b0i : b0o;
  const float* Wh = isIn ? Whi : Who;
  const float* bh = isIn ? bhi : bho;
  const float* Wl = isIn ? Wli : Wlo;
  const float* bl = isIn ? bli : blo;
  const float* w0i = isIn ? w0ii : w0io;
  float* efn = isIn ? efni : efno;

  const int tid  = threadIdx.x;
  const int lane = tid & 63;
  const int wo   = tid >> 6;      // wave 0..3 -> o cols wo*32..+32
  const int lm   = lane & 15;
  const int lg   = lane >> 4;

  // ---- stage small per-e vectors to LDS ----
  if (tid < 128)       w0s[tid]       = W0[(size_t)e * DD + tid];
  else if (tid < 256)  b0s[tid - 128] = b0[(size_t)e * DD + tid - 128];
  const float wi  = w0i[e];
  const float blv = bl[e];

  // ---- per-lane o constants (o = wo*32 + n*16 + lm) ----
  float bhv[2][2], wlv[2];
  #pragma unroll
  for (int n = 0; n < 2; ++n) {
    const int o = wo * 32 + n * 16 + lm;
    bhv[0][n] = bh[(size_t)e * DD + o];
    bhv[1][n] = bh[((size_t)E_TOT + e) * DD + o];
    wlv[n]    = Wl[(size_t)e * DD + o];
  }

  // ---- W fragments (proven layout): lane(lm,lg) holds
  //      W[o = wo*32+n*16+lm][k = kk*32+lg*8 .. +7]
  bf16x8 wfrag[2][4][2];
  #pragma unroll
  for (int l = 0; l < 2; ++l) {
    const float* Wg = Wh + ((size_t)l * E_TOT + e) * (DD * DD);
    #pragma unroll
    for (int kk = 0; kk < 4; ++kk)
      #pragma unroll
      for (int n = 0; n < 2; ++n) {
        const float* p = Wg + (wo * 32 + n * 16 + lm) * DD + kk * 32 + lg * 8;
        const float4 a = *(const float4*)p;
        const float4 c = *(const float4*)(p + 4);
        u32x4 u;
        u[0] = pkrn(a.x, a.y);
        u[1] = pkrn(a.z, a.w);
        u[2] = pkrn(c.x, c.y);
        u[3] = pkrn(c.z, c.w);
        wfrag[l][kk][n] = __builtin_bit_cast(bf16x8, u);
      }
  }

  const int tl = tid >> 3;    // 0..31 (local t row, for L0)
  const int q  = tid & 7;     // d-chunk q*16..+15

  u16* x0p = xP[0];
  u16* x1p = xP[1];

  // L0 writer: 16 sins -> one swizzled b128 store into x0 plane.
  auto L0 = [&](int it) {
    const float dom = (float)(it * 32 + tl) * tstep;
    #pragma unroll
    for (int c = 0; c < 2; ++c) {
      const int d = q * 16 + c * 8;
      const float4 wa = *(const float4*)&w0s[d];
      const float4 wb = *(const float4*)&w0s[d + 4];
      const float4 ba = *(const float4*)&b0s[d];
      const float4 bb = *(const float4*)&b0s[d + 4];
      u32x4 u;
      u[0] = pkrn(__sinf(wi * (wa.x * dom + ba.x)), __sinf(wi * (wa.y * dom + ba.y)));
      u[1] = pkrn(__sinf(wi * (wa.z * dom + ba.z)), __sinf(wi * (wa.w * dom + ba.w)));
      u[2] = pkrn(__sinf(wi * (wb.x * dom + bb.x)), __sinf(wi * (wb.y * dom + bb.y)));
      u[3] = pkrn(__sinf(wi * (wb.z * dom + bb.z)), __sinf(wi * (wb.w * dom + bb.w)));
      *(u16x8*)&x0p[swz(tl, d)] = __builtin_bit_cast(u16x8, u);
    }
  };

  __syncthreads();   // w0s/b0s ready
  L0(0);
  __syncthreads();   // x0(0) ready

  for (int it = 0; it < NIT; ++it) {
    f32x4 acc[2][2];

    // ---- hidden layer 1: acc = x0 . W1^T ----
    #pragma unroll
    for (int m = 0; m < 2; ++m)
      #pragma unroll
      for (int n = 0; n < 2; ++n) acc[m][n] = (f32x4){0.f, 0.f, 0.f, 0.f};
    #pragma unroll
    for (int kk = 0; kk < 4; ++kk) {
      const int kb = kk * 32 + lg * 8;
      bf16x8 ah[2];
      #pragma unroll
      for (int m = 0; m < 2; ++m)
        ah[m] = *(const bf16x8*)&x0p[swz(m * 16 + lm, kb)];
      #pragma unroll
      for (int m = 0; m < 2; ++m)
        #pragma unroll
        for (int n = 0; n < 2; ++n)
          acc[m][n] = __builtin_amdgcn_mfma_f32_16x16x32_bf16(ah[m], wfrag[0][kk][n], acc[m][n], 0, 0, 0);
    }
    // ---- act1 -> x1 plane (proven map: col=lm -> o, row=lg*4+r -> t) ----
    #pragma unroll
    for (int m = 0; m < 2; ++m)
      #pragma unroll
      for (int n = 0; n < 2; ++n) {
        const int o = wo * 32 + n * 16 + lm;
        const int t = m * 16 + lg * 4;
        const u32 p0 = pkrn(__sinf(acc[m][n][0] + bhv[0][n]), __sinf(acc[m][n][1] + bhv[0][n]));
        const u32 p1 = pkrn(__sinf(acc[m][n][2] + bhv[0][n]), __sinf(acc[m][n][3] + bhv[0][n]));
        x1p[swz(t + 0, o)] = (u16)p0;
        x1p[swz(t + 1, o)] = (u16)(p0 >> 16);
        x1p[swz(t + 2, o)] = (u16)p1;
        x1p[swz(t + 3, o)] = (u16)(p1 >> 16);
      }
    __syncthreads();   // BAR_A: x1 ready; all x0 reads done

    // ---- hidden layer 2: acc = x1 . W2^T ----
    #pragma unroll
    for (int m = 0; m < 2; ++m)
      #pragma unroll
      for (int n = 0; n < 2; ++n) acc[m][n] = (f32x4){0.f, 0.f, 0.f, 0.f};
    #pragma unroll
    for (int kk = 0; kk < 4; ++kk) {
      const int kb = kk * 32 + lg * 8;
      bf16x8 ah[2];
      #pragma unroll
      for (int m = 0; m < 2; ++m)
        ah[m] = *(const bf16x8*)&x1p[swz(m * 16 + lm, kb)];
      #pragma unroll
      for (int m = 0; m < 2; ++m)
        #pragma unroll
        for (int n = 0; n < 2; ++n)
          acc[m][n] = __builtin_amdgcn_mfma_f32_16x16x32_bf16(ah[m], wfrag[1][kk][n], acc[m][n], 0, 0, 0);
    }

    // ---- final layer in-register (consumes acc -> 8 scalars) ----
    #pragma unroll
    for (int m = 0; m < 2; ++m) {
      float p[4];
      #pragma unroll
      for (int r = 0; r < 4; ++r)
        p[r] = wlv[0] * __sinf(acc[m][0][r] + bhv[1][0])
             + wlv[1] * __sinf(acc[m][1][r] + bhv[1][1]);
      #pragma unroll
      for (int r = 0; r < 4; ++r) {
        p[r] += __shfl_xor(p[r], 1);
        p[r] += __shfl_xor(p[r], 2);
        p[r] += __shfl_xor(p[r], 4);
        p[r] += __shfl_xor(p[r], 8);
      }
      if (lm == 0) {
        #pragma unroll
        for (int r = 0; r < 4; ++r)
          yPart[wo * 32 + m * 16 + lg * 4 + r] = p[r];
      }
    }

    // ---- L0(it+1) in the acc-dead shadow (x0 reads all pre-BAR_A) ----
    if (it + 1 < NIT) L0(it + 1);

    __syncthreads();   // BAR_B: yPart + x0(it+1) ready; x1 reads done

    if (tid < 32) {
      const float s = yPart[tid] + yPart[32 + tid] + yPart[64 + tid] + yPart[96 + tid];
      efn[(size_t)(it * 32 + tid) * EF_W + CCc + e] = s + blv;
    }
    // yPart next written after BAR_A(it+1) -> epilogue reads race-free.
  }
}

// ---------------------------------------------------------------------------
// merged normalize: grid T_INc + T_OUTc
__global__ void normalize_all(float* __restrict__ efn_in, float* __restrict__ efn_out)
{
  const int tb = blockIdx.x;
  float* row = (tb < T_INc) ? (efn_in + (size_t)tb * EF_W)
                            : (efn_out + (size_t)(tb - T_INc) * EF_W);
  const int c = threadIdx.x;   // 64
  float v[16];
  float s = 1.0f;
  #pragma unroll
  for (int n = 0; n < 16; ++n) {
    v[n] = row[CCc + n * CCc + c];
    s += v[n] * v[n];
  }
  const float inv = 1.0f / sqrtf(s);
  row[c] = inv;
  #pragma unroll
  for (int n = 0; n < 16; ++n)
    row[CCc + n * CCc + c] = v[n] * inv;
}

// coeffs: block (n, b), 512 thr = 64 c x 8 t-chunks, LDS reduce.
__global__ __launch_bounds__(512) void coeffs_kernel(
    const float* __restrict__ x_enc, const float* __restrict__ x_mark_enc,
    const float* __restrict__ efn_in, float* __restrict__ flat_in)
{
  const int n  = blockIdx.x;   // 17
  const int b  = blockIdx.y;   // 32
  const int c  = threadIdx.x & 63;
  const int ch = threadIdx.x >> 6;   // 0..7
  __shared__ float red[8][64];
  float acc = 0.0f;
  #pragma unroll 4
  for (int t = ch * 64; t < ch * 64 + 64; ++t)
    acc += x_enc[((size_t)b * T_INc + t) * CCc + c]
         * efn_in[(size_t)t * EF_W + n * CCc + c];
  red[ch][c] = acc;
  __syncthreads();
  if (ch == 0) {
    #pragma unroll
    for (int k = 1; k < 8; ++k) acc += red[k][c];
    flat_in[b * LIN_I + n * CCc + c] = acc;
    if (n == 0 && c < 4)
      flat_in[b * LIN_I + EF_W + c] =
          x_mark_enc[((size_t)b * T_INc + (T_INc - 1)) * 4 + c];
  }
}

// Wlin transpose (for coalesced GEMV)
__global__ __launch_bounds__(256) void transpose_lin(const float* __restrict__ W,
                                                     float* __restrict__ Wt)
{
  __shared__ float tile[32][33];
  const int j0 = blockIdx.x * 32;
  const int o0 = blockIdx.y * 32;
  const int tx = threadIdx.x & 31, ty = threadIdx.x >> 5;  // ty 0..7
  #pragma unroll
  for (int r = 0; r < 32; r += 8) {
    const int o = o0 + ty + r, j = j0 + tx;
    tile[ty + r][tx] = (o < LIN_O && j < LIN_I) ? W[(size_t)o * LIN_I + j] : 0.f;
  }
  __syncthreads();
  #pragma unroll
  for (int r = 0; r < 32; r += 8) {
    const int j = j0 + ty + r, o = o0 + tx;
    if (j < LIN_I && o < LIN_O) Wt[(size_t)j * LIN_O + o] = tile[tx][ty + r];
  }
}

// linear (transposed W): block (o-tile, b), 256 thr = 64 o x 4 j-chunks.
__global__ __launch_bounds__(256) void linear_t_kernel(
    const float* __restrict__ flat_in, const float* __restrict__ Wt,
    const float* __restrict__ blin, float* __restrict__ pred)
{
  const int og = blockIdx.x;   // 17
  const int b  = blockIdx.y;   // 32
  const int c  = threadIdx.x & 63;
  const int ch = threadIdx.x >> 6;
  const int o  = og * 64 + c;
  __shared__ float red[4][64];
  const float* xi = flat_in + b * LIN_I;
  float acc = 0.0f;
  #pragma unroll 4
  for (int j = ch * 273; j < ch * 273 + 273; ++j)
    acc += Wt[(size_t)j * LIN_O + o] * xi[j];
  red[ch][c] = acc;
  __syncthreads();
  if (ch == 0)
    pred[b * LIN_O + o] = acc + red[1][c] + red[2][c] + red[3][c] + blin[o];
}

// fallback row-major linear (if ws too small for Wt)
__global__ void linear_row_kernel(const float* __restrict__ flat_in,
                                  const float* __restrict__ Wlin,
                                  const float* __restrict__ blin,
                                  float* __restrict__ pred)
{
  const int o = blockIdx.x * 64 + threadIdx.x;
  const int b = blockIdx.y;
  const float* w  = Wlin + (size_t)o * LIN_I;
  const float* xi = flat_in + b * LIN_I;
  float acc = blin[o];
  for (int j = 0; j < LIN_I; ++j) acc += w[j] * xi[j];
  pred[b * LIN_O + o] = acc;
}

__global__ void recon_kernel(const float* __restrict__ pred,
                             const float* __restrict__ efn_out,
                             float* __restrict__ out)
{
  const int b = blockIdx.y;
  const int t = blockIdx.x * 4 + (threadIdx.x >> 6);
  const int c = threadIdx.x & 63;
  float acc = 0.0f;
  #pragma unroll
  for (int n = 0; n < NB1; ++n)
    acc += pred[b * LIN_O + n * CCc + c]
         * efn_out[(size_t)t * EF_W + n * CCc + c];
  out[((size_t)b * T_OUTc + t) * CCc + c] = acc;
}

// ---------------------------------------------------------------------------
extern "C" void kernel_launch(void* const* d_in, const int* in_sizes, int n_in,
                              void* d_out, int out_size, void* d_ws, size_t ws_size,
                              hipStream_t stream)
{
  const float* x_enc      = (const float*)d_in[0];
  const float* x_mark_enc = (const float*)d_in[1];
  const float* W0_in  = (const float*)d_in[4];
  const float* b0_in  = (const float*)d_in[5];
  const float* Wh_in  = (const float*)d_in[6];
  const float* bh_in  = (const float*)d_in[7];
  const float* Wl_in  = (const float*)d_in[8];
  const float* bl_in  = (const float*)d_in[9];
  const float* w0i_in = (const float*)d_in[10];
  const float* W0_out  = (const float*)d_in[11];
  const float* b0_out  = (const float*)d_in[12];
  const float* Wh_out  = (const float*)d_in[13];
  const float* bh_out  = (const float*)d_in[14];
  const float* Wl_out  = (const float*)d_in[15];
  const float* bl_out  = (const float*)d_in[16];
  const float* w0i_out = (const float*)d_in[17];
  const float* Wlin = (const float*)d_in[18];
  const float* blin = (const float*)d_in[19];

  float* ws      = (float*)d_ws;
  float* efn_in  = ws;                                   // 512*1088
  float* efn_out = efn_in + (size_t)T_INc * EF_W;        // 256*1088
  float* flat_in = efn_out + (size_t)T_OUTc * EF_W;      // 32*1092
  float* pred    = flat_in + (size_t)BBc * LIN_I;        // 32*1088
  float* Wt      = pred + (size_t)BBc * LIN_O;           // 1092*1088
  const size_t needWt = ((size_t)(Wt - ws) + (size_t)LIN_I * LIN_O) * sizeof(float);
  const bool useWt = (ws_size >= needWt);

  eigen_persist<<<dim3(2 * E_TOT), dim3(256), 0, stream>>>(
      W0_in, b0_in, Wh_in, bh_in, Wl_in, bl_in, w0i_in, efn_in,
      W0_out, b0_out, Wh_out, bh_out, Wl_out, bl_out, w0i_out, efn_out);

  normalize_all<<<dim3(T_INc + T_OUTc), dim3(64), 0, stream>>>(efn_in, efn_out);

  coeffs_kernel<<<dim3(NB1, BBc), dim3(512), 0, stream>>>(x_enc, x_mark_enc, efn_in, flat_in);

  if (useWt) {
    transpose_lin<<<dim3((LIN_I + 31) / 32, (LIN_O + 31) / 32), dim3(256), 0, stream>>>(Wlin, Wt);
    linear_t_kernel<<<dim3(NB1, BBc), dim3(256), 0, stream>>>(flat_in, Wt, blin, pred);
  } else {
    linear_row_kernel<<<dim3(NB1, BBc), dim3(64), 0, stream>>>(flat_in, Wlin, blin, pred);
  }

  recon_kernel<<<dim3(T_OUTc / 4, BBc), dim3(256), 0, stream>>>(pred, efn_out, (float*)d_out);
}

// Round 18
// 177.365 us; speedup vs baseline: 1.1043x; 1.1043x over previous
//
#include <hip/hip_runtime.h>
#include <hip/hip_bf16.h>
#include <math.h>

// SIREN eigenfunction banks + small linear head.
// eigen: ROUND-16 structure exactly (persistent-e, 256 thr / 32-t iters,
// 3 barriers, launch_bounds(256,4), VGPR 64). ONLY change: all sins via
// hardware v_sin_f32 (input in revolutions; 1/2pi folded into constants).

typedef short  bf16x8 __attribute__((ext_vector_type(8)));
typedef float  f32x4  __attribute__((ext_vector_type(4)));
typedef unsigned short u16;
typedef u16    u16x8  __attribute__((ext_vector_type(8)));
typedef unsigned int u32;
typedef u32    u32x4  __attribute__((ext_vector_type(4)));

constexpr int DD    = 128;
constexpr int E_TOT = 1024;
constexpr int T_INc = 512;
constexpr int T_OUTc= 256;
constexpr int BBc   = 32;
constexpr int CCc   = 64;
constexpr int NB1   = 17;
constexpr int EF_W  = NB1 * CCc;     // 1088
constexpr int LIN_I = EF_W + 4;      // 1092
constexpr int LIN_O = EF_W;          // 1088

#define INV2PI 0.15915494309189535f

// hardware sin: v_sin_f32 computes sin(2*pi*x) — pass revolutions.
__device__ __forceinline__ float hsin(float rev) {
  return __builtin_amdgcn_sinf(rev);
}

// packed RNE pair via compiler intrinsic: low 16 bits = cvt(a), high = cvt(b)
__device__ __forceinline__ u32 pkrn(float a, float b) {
  __hip_bfloat162 h = __float22bfloat162_rn(float2{a, b});
  u32 r;
  __builtin_memcpy(&r, &h, 4);
  return r;
}

// XOR-swizzled element index into a row-major [rows][128] u16 LDS plane.
// byte = row*256 + ((col*2) ^ ((row&15)<<4)); 16B-chunk preserving. (proven)
__device__ __forceinline__ int swz(int row, int col) {
  return row * DD + ((((col << 1) ^ ((row & 15) << 4)) >> 1));
}

// ---------------------------------------------------------------------------
// eigen_persist: grid = 2*E_TOT. Blocks [0,1024): T_IN; [1024,2048): T_OUT.
// 4 waves = wo 0..3; per 32-t iter each wave computes 32t x 32o.
// Barriers per iter: (1) x0 ready, (2) x1 ready, (3) yPart ready. (R16-proven)
// ---------------------------------------------------------------------------
__global__ __launch_bounds__(256, 4) void eigen_persist(
    const float* __restrict__ W0i, const float* __restrict__ b0i,
    const float* __restrict__ Whi, const float* __restrict__ bhi,
    const float* __restrict__ Wli, const float* __restrict__ bli,
    const float* __restrict__ w0ii, float* __restrict__ efni,
    const float* __restrict__ W0o, const float* __restrict__ b0o,
    const float* __restrict__ Who, const float* __restrict__ bho,
    const float* __restrict__ Wlo, const float* __restrict__ blo,
    const float* __restrict__ w0io, float* __restrict__ efno)
{
  __shared__ u16 xP[2][4096];          // x0 / x1 planes (32x128 bf16, swizzled)
  __shared__ float yPart[4 * 32];      // per-wo partial y[t]
  __shared__ float w0s[128], b0s[128]; // pre-scaled by wi/(2*pi)

  const bool isIn = (blockIdx.x < E_TOT);
  const int  e    = blockIdx.x & (E_TOT - 1);
  const int  NIT  = isIn ? (T_INc / 32) : (T_OUTc / 32);
  const float tstep = isIn ? (1.0f / (float)(T_INc - 1)) : (1.0f / (float)(T_OUTc - 1));
  const float* W0 = isIn ? W0i : W0o;
  const float* b0 = isIn ? b0i : b0o;
  const float* Wh = isIn ? Whi : Who;
  const float* bh = isIn ? bhi : bho;
  const float* Wl = isIn ? Wli : Wlo;
  const float* bl = isIn ? bli : blo;
  const float* w0i = isIn ? w0ii : w0io;
  float* efn = isIn ? efni : efno;

  const int tid  = threadIdx.x;
  const int lane = tid & 63;
  const int wo   = tid >> 6;      // wave 0..3 -> o cols wo*32..+32
  const int lm   = lane & 15;
  const int lg   = lane >> 4;

  const float wi  = w0i[e];
  const float blv = bl[e];

  // ---- stage small per-e vectors to LDS, pre-scaled to revolutions ----
  if (tid < 128)       w0s[tid]       = W0[(size_t)e * DD + tid] * (wi * INV2PI);
  else if (tid < 256)  b0s[tid - 128] = b0[(size_t)e * DD + tid - 128] * (wi * INV2PI);

  // ---- per-lane o constants (o = wo*32 + n*16 + lm); bh pre-scaled ----
  float bhv[2][2], wlv[2];
  #pragma unroll
  for (int n = 0; n < 2; ++n) {
    const int o = wo * 32 + n * 16 + lm;
    bhv[0][n] = bh[(size_t)e * DD + o] * INV2PI;
    bhv[1][n] = bh[((size_t)E_TOT + e) * DD + o] * INV2PI;
    wlv[n]    = Wl[(size_t)e * DD + o];
  }

  // ---- W fragments (proven layout): lane(lm,lg) holds
  //      W[o = wo*32+n*16+lm][k = kk*32+lg*8 .. +7]
  bf16x8 wfrag[2][4][2];
  #pragma unroll
  for (int l = 0; l < 2; ++l) {
    const float* Wg = Wh + ((size_t)l * E_TOT + e) * (DD * DD);
    #pragma unroll
    for (int kk = 0; kk < 4; ++kk)
      #pragma unroll
      for (int n = 0; n < 2; ++n) {
        const float* p = Wg + (wo * 32 + n * 16 + lm) * DD + kk * 32 + lg * 8;
        const float4 a = *(const float4*)p;
        const float4 c = *(const float4*)(p + 4);
        u32x4 u;
        u[0] = pkrn(a.x, a.y);
        u[1] = pkrn(a.z, a.w);
        u[2] = pkrn(c.x, c.y);
        u[3] = pkrn(c.z, c.w);
        wfrag[l][kk][n] = __builtin_bit_cast(bf16x8, u);
      }
  }
  __syncthreads();   // w0s/b0s ready

  const int tl = tid >> 3;    // 0..31 (local t row, for L0)
  const int q  = tid & 7;     // d-chunk q*16..+15

  u16* x0p = xP[0];
  u16* x1p = xP[1];

  for (int it = 0; it < NIT; ++it) {
    // ---- layer 0 -> x0 plane (rev = w0s*dom + b0s, one fma + v_sin) ----
    {
      const float dom = (float)(it * 32 + tl) * tstep;
      #pragma unroll
      for (int c = 0; c < 2; ++c) {
        const int d = q * 16 + c * 8;
        const float4 wa = *(const float4*)&w0s[d];
        const float4 wb = *(const float4*)&w0s[d + 4];
        const float4 ba = *(const float4*)&b0s[d];
        const float4 bb = *(const float4*)&b0s[d + 4];
        u32x4 u;
        u[0] = pkrn(hsin(fmaf(wa.x, dom, ba.x)), hsin(fmaf(wa.y, dom, ba.y)));
        u[1] = pkrn(hsin(fmaf(wa.z, dom, ba.z)), hsin(fmaf(wa.w, dom, ba.w)));
        u[2] = pkrn(hsin(fmaf(wb.x, dom, bb.x)), hsin(fmaf(wb.y, dom, bb.y)));
        u[3] = pkrn(hsin(fmaf(wb.z, dom, bb.z)), hsin(fmaf(wb.w, dom, bb.w)));
        *(u16x8*)&x0p[swz(tl, d)] = __builtin_bit_cast(u16x8, u);
      }
    }
    __syncthreads();   // (1) x0 ready

    f32x4 acc[2][2];

    // ---- hidden layer 1: acc = x0 . W1^T ----
    #pragma unroll
    for (int m = 0; m < 2; ++m)
      #pragma unroll
      for (int n = 0; n < 2; ++n) acc[m][n] = (f32x4){0.f, 0.f, 0.f, 0.f};
    #pragma unroll
    for (int kk = 0; kk < 4; ++kk) {
      const int kb = kk * 32 + lg * 8;
      bf16x8 ah[2];
      #pragma unroll
      for (int m = 0; m < 2; ++m)
        ah[m] = *(const bf16x8*)&x0p[swz(m * 16 + lm, kb)];
      #pragma unroll
      for (int m = 0; m < 2; ++m)
        #pragma unroll
        for (int n = 0; n < 2; ++n)
          acc[m][n] = __builtin_amdgcn_mfma_f32_16x16x32_bf16(ah[m], wfrag[0][kk][n], acc[m][n], 0, 0, 0);
    }
    // ---- act1 -> x1 plane (rev = acc/2pi + bh'; proven store map) ----
    #pragma unroll
    for (int m = 0; m < 2; ++m)
      #pragma unroll
      for (int n = 0; n < 2; ++n) {
        const int o = wo * 32 + n * 16 + lm;
        const int t = m * 16 + lg * 4;
        const u32 p0 = pkrn(hsin(fmaf(acc[m][n][0], INV2PI, bhv[0][n])),
                            hsin(fmaf(acc[m][n][1], INV2PI, bhv[0][n])));
        const u32 p1 = pkrn(hsin(fmaf(acc[m][n][2], INV2PI, bhv[0][n])),
                            hsin(fmaf(acc[m][n][3], INV2PI, bhv[0][n])));
        x1p[swz(t + 0, o)] = (u16)p0;
        x1p[swz(t + 1, o)] = (u16)(p0 >> 16);
        x1p[swz(t + 2, o)] = (u16)p1;
        x1p[swz(t + 3, o)] = (u16)(p1 >> 16);
      }
    __syncthreads();   // (2) x1 ready (and all x0 reads done)

    // ---- hidden layer 2: acc = x1 . W2^T ----
    #pragma unroll
    for (int m = 0; m < 2; ++m)
      #pragma unroll
      for (int n = 0; n < 2; ++n) acc[m][n] = (f32x4){0.f, 0.f, 0.f, 0.f};
    #pragma unroll
    for (int kk = 0; kk < 4; ++kk) {
      const int kb = kk * 32 + lg * 8;
      bf16x8 ah[2];
      #pragma unroll
      for (int m = 0; m < 2; ++m)
        ah[m] = *(const bf16x8*)&x1p[swz(m * 16 + lm, kb)];
      #pragma unroll
      for (int m = 0; m < 2; ++m)
        #pragma unroll
        for (int n = 0; n < 2; ++n)
          acc[m][n] = __builtin_amdgcn_mfma_f32_16x16x32_bf16(ah[m], wfrag[1][kk][n], acc[m][n], 0, 0, 0);
    }

    // ---- final layer in-register: lane holds preact2[t][o], o=wo*32+n*16+lm,
    //      t=m*16+lg*4+r; reduce over lm (o) via shfl_xor, cross-wo via yPart.
    #pragma unroll
    for (int m = 0; m < 2; ++m) {
      float p[4];
      #pragma unroll
      for (int r = 0; r < 4; ++r)
        p[r] = wlv[0] * hsin(fmaf(acc[m][0][r], INV2PI, bhv[1][0]))
             + wlv[1] * hsin(fmaf(acc[m][1][r], INV2PI, bhv[1][1]));
      #pragma unroll
      for (int r = 0; r < 4; ++r) {
        p[r] += __shfl_xor(p[r], 1);
        p[r] += __shfl_xor(p[r], 2);
        p[r] += __shfl_xor(p[r], 4);
        p[r] += __shfl_xor(p[r], 8);
      }
      if (lm == 0) {
        #pragma unroll
        for (int r = 0; r < 4; ++r)
          yPart[wo * 32 + m * 16 + lg * 4 + r] = p[r];
      }
    }
    __syncthreads();   // (3) yPart ready (and all x1 reads done)

    if (tid < 32) {
      const float s = yPart[tid] + yPart[32 + tid] + yPart[64 + tid] + yPart[96 + tid];
      efn[(size_t)(it * 32 + tid) * EF_W + CCc + e] = s + blv;
    }
    // next-iter L0 writes x0 (last read before barrier 2); yPart next written
    // after next barrier (2) -> tid<32 epilogue reads race-free. (R16-proven)
  }
}

// ---------------------------------------------------------------------------
// merged normalize: grid T_INc + T_OUTc
__global__ void normalize_all(float* __restrict__ efn_in, float* __restrict__ efn_out)
{
  const int tb = blockIdx.x;
  float* row = (tb < T_INc) ? (efn_in + (size_t)tb * EF_W)
                            : (efn_out + (size_t)(tb - T_INc) * EF_W);
  const int c = threadIdx.x;   // 64
  float v[16];
  float s = 1.0f;
  #pragma unroll
  for (int n = 0; n < 16; ++n) {
    v[n] = row[CCc + n * CCc + c];
    s += v[n] * v[n];
  }
  const float inv = 1.0f / sqrtf(s);
  row[c] = inv;
  #pragma unroll
  for (int n = 0; n < 16; ++n)
    row[CCc + n * CCc + c] = v[n] * inv;
}

// coeffs: block (n, b), 512 thr = 64 c x 8 t-chunks, LDS reduce.
__global__ __launch_bounds__(512) void coeffs_kernel(
    const float* __restrict__ x_enc, const float* __restrict__ x_mark_enc,
    const float* __restrict__ efn_in, float* __restrict__ flat_in)
{
  const int n  = blockIdx.x;   // 17
  const int b  = blockIdx.y;   // 32
  const int c  = threadIdx.x & 63;
  const int ch = threadIdx.x >> 6;   // 0..7
  __shared__ float red[8][64];
  float acc = 0.0f;
  #pragma unroll 4
  for (int t = ch * 64; t < ch * 64 + 64; ++t)
    acc += x_enc[((size_t)b * T_INc + t) * CCc + c]
         * efn_in[(size_t)t * EF_W + n * CCc + c];
  red[ch][c] = acc;
  __syncthreads();
  if (ch == 0) {
    #pragma unroll
    for (int k = 1; k < 8; ++k) acc += red[k][c];
    flat_in[b * LIN_I + n * CCc + c] = acc;
    if (n == 0 && c < 4)
      flat_in[b * LIN_I + EF_W + c] =
          x_mark_enc[((size_t)b * T_INc + (T_INc - 1)) * 4 + c];
  }
}

// Wlin transpose (for coalesced GEMV)
__global__ __launch_bounds__(256) void transpose_lin(const float* __restrict__ W,
                                                     float* __restrict__ Wt)
{
  __shared__ float tile[32][33];
  const int j0 = blockIdx.x * 32;
  const int o0 = blockIdx.y * 32;
  const int tx = threadIdx.x & 31, ty = threadIdx.x >> 5;  // ty 0..7
  #pragma unroll
  for (int r = 0; r < 32; r += 8) {
    const int o = o0 + ty + r, j = j0 + tx;
    tile[ty + r][tx] = (o < LIN_O && j < LIN_I) ? W[(size_t)o * LIN_I + j] : 0.f;
  }
  __syncthreads();
  #pragma unroll
  for (int r = 0; r < 32; r += 8) {
    const int j = j0 + ty + r, o = o0 + tx;
    if (j < LIN_I && o < LIN_O) Wt[(size_t)j * LIN_O + o] = tile[tx][ty + r];
  }
}

// linear (transposed W): block (o-tile, b), 256 thr = 64 o x 4 j-chunks.
__global__ __launch_bounds__(256) void linear_t_kernel(
    const float* __restrict__ flat_in, const float* __restrict__ Wt,
    const float* __restrict__ blin, float* __restrict__ pred)
{
  const int og = blockIdx.x;   // 17
  const int b  = blockIdx.y;   // 32
  const int c  = threadIdx.x & 63;
  const int ch = threadIdx.x >> 6;
  const int o  = og * 64 + c;
  __shared__ float red[4][64];
  const float* xi = flat_in + b * LIN_I;
  float acc = 0.0f;
  #pragma unroll 4
  for (int j = ch * 273; j < ch * 273 + 273; ++j)
    acc += Wt[(size_t)j * LIN_O + o] * xi[j];
  red[ch][c] = acc;
  __syncthreads();
  if (ch == 0)
    pred[b * LIN_O + o] = acc + red[1][c] + red[2][c] + red[3][c] + blin[o];
}

// fallback row-major linear (if ws too small for Wt)
__global__ void linear_row_kernel(const float* __restrict__ flat_in,
                                  const float* __restrict__ Wlin,
                                  const float* __restrict__ blin,
                                  float* __restrict__ pred)
{
  const int o = blockIdx.x * 64 + threadIdx.x;
  const int b = blockIdx.y;
  const float* w  = Wlin + (size_t)o * LIN_I;
  const float* xi = flat_in + b * LIN_I;
  float acc = blin[o];
  for (int j = 0; j < LIN_I; ++j) acc += w[j] * xi[j];
  pred[b * LIN_O + o] = acc;
}

__global__ void recon_kernel(const float* __restrict__ pred,
                             const float* __restrict__ efn_out,
                             float* __restrict__ out)
{
  const int b = blockIdx.y;
  const int t = blockIdx.x * 4 + (threadIdx.x >> 6);
  const int c = threadIdx.x & 63;
  float acc = 0.0f;
  #pragma unroll
  for (int n = 0; n < NB1; ++n)
    acc += pred[b * LIN_O + n * CCc + c]
         * efn_out[(size_t)t * EF_W + n * CCc + c];
  out[((size_t)b * T_OUTc + t) * CCc + c] = acc;
}

// ---------------------------------------------------------------------------
extern "C" void kernel_launch(void* const* d_in, const int* in_sizes, int n_in,
                              void* d_out, int out_size, void* d_ws, size_t ws_size,
                              hipStream_t stream)
{
  const float* x_enc      = (const float*)d_in[0];
  const float* x_mark_enc = (const float*)d_in[1];
  const float* W0_in  = (const float*)d_in[4];
  const float* b0_in  = (const float*)d_in[5];
  const float* Wh_in  = (const float*)d_in[6];
  const float* bh_in  = (const float*)d_in[7];
  const float* Wl_in  = (const float*)d_in[8];
  const float* bl_in  = (const float*)d_in[9];
  const float* w0i_in = (const float*)d_in[10];
  const float* W0_out  = (const float*)d_in[11];
  const float* b0_out  = (const float*)d_in[12];
  const float* Wh_out  = (const float*)d_in[13];
  const float* bh_out  = (const float*)d_in[14];
  const float* Wl_out  = (const float*)d_in[15];
  const float* bl_out  = (const float*)d_in[16];
  const float* w0i_out = (const float*)d_in[17];
  const float* Wlin = (const float*)d_in[18];
  const float* blin = (const float*)d_in[19];

  float* ws      = (float*)d_ws;
  float* efn_in  = ws;                                   // 512*1088
  float* efn_out = efn_in + (size_t)T_INc * EF_W;        // 256*1088
  float* flat_in = efn_out + (size_t)T_OUTc * EF_W;      // 32*1092
  float* pred    = flat_in + (size_t)BBc * LIN_I;        // 32*1088
  float* Wt      = pred + (size_t)BBc * LIN_O;           // 1092*1088
  const size_t needWt = ((size_t)(Wt - ws) + (size_t)LIN_I * LIN_O) * sizeof(float);
  const bool useWt = (ws_size >= needWt);

  eigen_persist<<<dim3(2 * E_TOT), dim3(256), 0, stream>>>(
      W0_in, b0_in, Wh_in, bh_in, Wl_in, bl_in, w0i_in, efn_in,
      W0_out, b0_out, Wh_out, bh_out, Wl_out, bl_out, w0i_out, efn_out);

  normalize_all<<<dim3(T_INc + T_OUTc), dim3(64), 0, stream>>>(efn_in, efn_out);

  coeffs_kernel<<<dim3(NB1, BBc), dim3(512), 0, stream>>>(x_enc, x_mark_enc, efn_in, flat_in);

  if (useWt) {
    transpose_lin<<<dim3((LIN_I + 31) / 32, (LIN_O + 31) / 32), dim3(256), 0, stream>>>(Wlin, Wt);
    linear_t_kernel<<<dim3(NB1, BBc), dim3(256), 0, stream>>>(flat_in, Wt, blin, pred);
  } else {
    linear_row_kernel<<<dim3(NB1, BBc), dim3(64), 0, stream>>>(flat_in, Wlin, blin, pred);
  }

  recon_kernel<<<dim3(T_OUTc / 4, BBc), dim3(256), 0, stream>>>(pred, efn_out, (float*)d_out);
}